// Round 6
// baseline (264.977 us; speedup 1.0000x reference)
//
#include <hip/hip_runtime.h>
#include <hip/hip_bf16.h>
#include <math.h>

#define B 128
#define L 400
#define S 30
#define V 50000
#define EMB 128
#define H 512
#define M 512
#define OOV 30
#define H3 1536
#define VO (V + OOV)

// ---- output layout (floats) ----
#define O_HN    (B * VO)
#define O_WCTX  (O_HN + B * H)
#define O_WATTN (O_WCTX + B * M)
#define O_PGEN  (O_WATTN + B * L)
#define O_WCOV  (O_PGEN + B)

typedef short bf16x8 __attribute__((ext_vector_type(8)));
typedef float f32x4 __attribute__((ext_vector_type(4)));

__device__ __forceinline__ unsigned pk2(float a, float b) {
    union { __hip_bfloat162 h; unsigned u; } cv;
    cv.h = __float22bfloat162_rn(make_float2(a, b));
    return cv.u;
}

__device__ __forceinline__ float fast_tanh(float x) {
    float e = __expf(2.f * x);
    return 1.f - 2.f * __builtin_amdgcn_rcpf(e + 1.f);
}

// ---- fused setup: bias-broadcast C buffers, zero scores, y-emb gather, weight cvt ----
__global__ void k_setup(const float* __restrict__ bih, const float* __restrict__ bhh,
                        const float* __restrict__ bdpw, const float* __restrict__ bdps,
                        const float* __restrict__ v1b, const float* __restrict__ emb,
                        const int* __restrict__ y,
                        float* gi, float* gh, float* dpw, float* dps, float* hid,
                        float* wscore, float* sscore, float* yemb,
                        const float* __restrict__ wih, const float* __restrict__ whh,
                        const float* __restrict__ wdpw, const float* __restrict__ wdps,
                        const float* __restrict__ wmpw, const float* __restrict__ wmps,
                        const float* __restrict__ v1,
                        short* o_ih, short* o_hh, short* o_dpw, short* o_dps,
                        short* o_mpw, short* o_mps, short* o_v1) {
    int bb = blockIdx.x;
    if (bb < 2583) {
        int i = bb * 256 + threadIdx.x;
        if (i < 196608) { gi[i] = bih[i % 1536]; return; }
        i -= 196608;
        if (i < 196608) { gh[i] = bhh[i % 1536]; return; }
        i -= 196608;
        if (i < 65536) { dpw[i] = bdpw[i & 511]; return; }
        i -= 65536;
        if (i < 65536) { dps[i] = bdps[i & 511]; return; }
        i -= 65536;
        if (i < 65536) { hid[i] = v1b[i & 511]; return; }
        i -= 65536;
        if (i < 51200) { wscore[i] = 0.f; return; }
        i -= 51200;
        if (i < 3840) { sscore[i] = 0.f; return; }
        i -= 3840;
        if (i < 16384) { int b = i >> 7, e = i & 127; yemb[i] = emb[(size_t)y[b] * EMB + e]; }
        return;
    }
    bb -= 2583;
    const float* src; short* dst;
    if      (bb < 96)  { src = wih;  dst = o_ih; }
    else if (bb < 480) { src = whh;  dst = o_hh;  bb -= 96; }
    else if (bb < 608) { src = wdpw; dst = o_dpw; bb -= 480; }
    else if (bb < 736) { src = wdps; dst = o_dps; bb -= 608; }
    else if (bb < 864) { src = wmpw; dst = o_mpw; bb -= 736; }
    else if (bb < 992) { src = wmps; dst = o_mps; bb -= 864; }
    else               { src = v1;   dst = o_v1;  bb -= 992; }
    size_t i = (size_t)bb * 2048 + threadIdx.x * 8;
    float4 a = *(const float4*)(src + i);
    float4 c = *(const float4*)(src + i + 4);
    uint4 w;
    w.x = pk2(a.x, a.y); w.y = pk2(a.z, a.w);
    w.z = pk2(c.x, c.y); w.w = pk2(c.z, c.w);
    *(uint4*)(dst + i) = w;
}

// stage 128 rows x 64 cols fp32 -> bf16 LDS [128][72]
__device__ __forceinline__ void stage_a(const float* __restrict__ src, int SK, int rmax,
                                        int t, short dst[128][72]) {
    int col = (t & 7) * 8;
    int r0 = t >> 3;
#pragma unroll
    for (int i = 0; i < 4; ++i) {
        int r = r0 + i * 32;
        int rr = r < rmax ? r : rmax;
        const float* p = src + (size_t)rr * SK + col;
        float4 a = *(const float4*)p;
        float4 c = *(const float4*)(p + 4);
        uint4 w;
        w.x = pk2(a.x, a.y); w.y = pk2(a.z, a.w);
        w.z = pk2(c.x, c.y); w.w = pk2(c.z, c.w);
        *(uint4*)&dst[r][col] = w;
    }
}

__device__ __forceinline__ void stage_b128bf(const short* __restrict__ src, int K,
                                             int t, short dst[128][72]) {
    int col = (t & 7) * 8;
    int r0 = t >> 3;
#pragma unroll
    for (int i = 0; i < 4; ++i) {
        int r = r0 + i * 32;
        *(bf16x8*)&dst[r][col] = *(const bf16x8*)(src + (size_t)r * K + col);
    }
}

// ---------- split-K skinny GEMM (M=128): C += A @ Bw^T, atomics, 2 fused jobs ----------
__global__ __launch_bounds__(256, 2) void k_mmsk(
        const float* __restrict__ A0, const short* __restrict__ B0, float* __restrict__ C0,
        int K0, int NT0, int KB0,
        const float* __restrict__ A1, const short* __restrict__ B1, float* __restrict__ C1,
        int K1, int NT1, int KB1) {
    __shared__ short As[128][72];
    __shared__ short Bs[128][72];
    int t = threadIdx.x, lane = t & 63, wv = t >> 6;
    int wr = wv >> 1, wc = wv & 1;
    int l15 = lane & 15, l4 = lane >> 4;

    int bb = blockIdx.x;
    const float* A; const short* Bb; float* C; int K, NT, KB;
    if (bb < NT0 * KB0) { A = A0; Bb = B0; C = C0; K = K0; NT = NT0; KB = KB0; }
    else { bb -= NT0 * KB0; A = A1; Bb = B1; C = C1; K = K1; NT = NT1; KB = KB1; }
    int nIdx = bb % NT, kIdx = bb / NT;
    int ldc = NT * 128;
    int nBase = nIdx * 128;
    int KC = K / KB;
    int kLo = kIdx * KC, kHi = kLo + KC;

    f32x4 acc[4][4] = {};
    for (int kc = kLo; kc < kHi; kc += 64) {
        stage_a(A + kc, K, 127, t, As);
        stage_b128bf(Bb + (size_t)nBase * K + kc, K, t, Bs);
        __syncthreads();
#pragma unroll
        for (int kk = 0; kk < 2; ++kk) {
            bf16x8 af[4], bq[4];
#pragma unroll
            for (int i = 0; i < 4; ++i)
                af[i] = *(const bf16x8*)&As[wr * 64 + i * 16 + l15][kk * 32 + l4 * 8];
#pragma unroll
            for (int j = 0; j < 4; ++j)
                bq[j] = *(const bf16x8*)&Bs[wc * 64 + j * 16 + l15][kk * 32 + l4 * 8];
#pragma unroll
            for (int i = 0; i < 4; ++i)
#pragma unroll
                for (int j = 0; j < 4; ++j)
                    acc[i][j] = __builtin_amdgcn_mfma_f32_16x16x32_bf16(
                        af[i], bq[j], acc[i][j], 0, 0, 0);
        }
        __syncthreads();
    }
#pragma unroll
    for (int i = 0; i < 4; ++i)
#pragma unroll
        for (int r = 0; r < 4; ++r) {
            int row = wr * 64 + i * 16 + l4 * 4 + r;
#pragma unroll
            for (int j = 0; j < 4; ++j) {
                int n = nBase + wc * 64 + j * 16 + l15;
                atomicAdd(&C[(size_t)row * ldc + n], acc[i][j][r]);
            }
        }
}

// ---------- vocab logits GEMM: C[128,V] = hid @ vd2w^T + bias ----------
__global__ __launch_bounds__(256, 2) void k_mm128(
        const float* __restrict__ Ap, const float* __restrict__ Bf,
        const float* __restrict__ bias, float* __restrict__ C, int K, int ldc, int Nlim) {
    __shared__ short As[128][72];
    __shared__ short Bs[128][72];
    int t = threadIdx.x, lane = t & 63, wv = t >> 6;
    int wr = wv >> 1, wc = wv & 1;
    int l15 = lane & 15, l4 = lane >> 4;
    int nBase = blockIdx.x * 128;
    int brmax = Nlim - 1 - nBase; if (brmax > 127) brmax = 127;

    f32x4 acc[4][4] = {};
    for (int kc = 0; kc < K; kc += 64) {
        stage_a(Ap + kc, K, 127, t, As);
        stage_a(Bf + (size_t)nBase * K + kc, K, brmax, t, Bs);
        __syncthreads();
#pragma unroll
        for (int kk = 0; kk < 2; ++kk) {
            bf16x8 af[4], bq[4];
#pragma unroll
            for (int i = 0; i < 4; ++i)
                af[i] = *(const bf16x8*)&As[wr * 64 + i * 16 + l15][kk * 32 + l4 * 8];
#pragma unroll
            for (int j = 0; j < 4; ++j)
                bq[j] = *(const bf16x8*)&Bs[wc * 64 + j * 16 + l15][kk * 32 + l4 * 8];
#pragma unroll
            for (int i = 0; i < 4; ++i)
#pragma unroll
                for (int j = 0; j < 4; ++j)
                    acc[i][j] = __builtin_amdgcn_mfma_f32_16x16x32_bf16(
                        af[i], bq[j], acc[i][j], 0, 0, 0);
        }
        __syncthreads();
    }
#pragma unroll
    for (int i = 0; i < 4; ++i)
#pragma unroll
        for (int r = 0; r < 4; ++r) {
            int row = wr * 64 + i * 16 + l4 * 4 + r;
#pragma unroll
            for (int j = 0; j < 4; ++j) {
                int n = nBase + wc * 64 + j * 16 + l15;
                if (n < Nlim) C[(size_t)row * ldc + n] = acc[i][j][r] + bias[n];
            }
        }
}

// ---------- fused word+sent attention feature GEMM + tanh + v-dot ----------
// 128x128 tile, 36 KB LDS, 4 blocks/CU target. grid (4, 430).
__global__ __launch_bounds__(256, 4) void k_feat(
        const float* __restrict__ wmb, const short* __restrict__ wbmpw,
        const float* __restrict__ dpw, const float* __restrict__ cov,
        const float* __restrict__ covp, const float* __restrict__ vw,
        float* __restrict__ wscore,
        const float* __restrict__ smb, const short* __restrict__ wbmps,
        const float* __restrict__ dps, const float* __restrict__ vs,
        float* __restrict__ sscore) {
    __shared__ short As[128][72];
    __shared__ short Bs[128][72];
    int t = threadIdx.x, lane = t & 63, wv = t >> 6;
    int wr = wv >> 1, wc = wv & 1;
    int l15 = lane & 15, l4 = lane >> 4;

    bool word = blockIdx.y < 400;
    const float* Ap; const short* Bbf; const float* dproj; const float* vvec; float* outp;
    int rowBase;
    if (word) { Ap = wmb; Bbf = wbmpw; dproj = dpw; vvec = vw; outp = wscore; rowBase = blockIdx.y * 128; }
    else      { Ap = smb; Bbf = wbmps; dproj = dps; vvec = vs; outp = sscore; rowBase = (blockIdx.y - 400) * 128; }
    int nBase = blockIdx.x * 128;
    const float* Asrc = Ap + (size_t)rowBase * 512;
    const short* Bsrc = Bbf + (size_t)nBase * 512;

    f32x4 acc[4][4] = {};
    for (int kc = 0; kc < 512; kc += 64) {
        stage_a(Asrc + kc, 512, 127, t, As);
        stage_b128bf(Bsrc + kc, 512, t, Bs);
        __syncthreads();
#pragma unroll
        for (int kk = 0; kk < 2; ++kk) {
            bf16x8 af[4], bq[4];
#pragma unroll
            for (int i = 0; i < 4; ++i)
                af[i] = *(const bf16x8*)&As[wr * 64 + i * 16 + l15][kk * 32 + l4 * 8];
#pragma unroll
            for (int j = 0; j < 4; ++j)
                bq[j] = *(const bf16x8*)&Bs[wc * 64 + j * 16 + l15][kk * 32 + l4 * 8];
#pragma unroll
            for (int i = 0; i < 4; ++i)
#pragma unroll
                for (int j = 0; j < 4; ++j)
                    acc[i][j] = __builtin_amdgcn_mfma_f32_16x16x32_bf16(
                        af[i], bq[j], acc[i][j], 0, 0, 0);
        }
        __syncthreads();
    }
    int dB = nBase + wc * 64;
    float vv[4], cp[4];
#pragma unroll
    for (int j = 0; j < 4; ++j) {
        int d = dB + j * 16 + l15;
        vv[j] = vvec[d];
        cp[j] = word ? covp[d] : 0.f;
    }
#pragma unroll
    for (int i = 0; i < 4; ++i) {
#pragma unroll
        for (int r = 0; r < 4; ++r) {
            int row = rowBase + wr * 64 + i * 16 + l4 * 4 + r;
            int b = word ? (row / 400) : (row / 30);
            float cv = word ? cov[row] : 0.f;
            float s = 0.f;
#pragma unroll
            for (int j = 0; j < 4; ++j) {
                float dpv = dproj[b * H + dB + j * 16 + l15];
                float f = acc[i][j][r] + dpv + cv * cp[j];
                s += vv[j] * fast_tanh(f);
            }
            s += __shfl_xor(s, 8, 16);
            s += __shfl_xor(s, 4, 16);
            s += __shfl_xor(s, 2, 16);
            s += __shfl_xor(s, 1, 16);
            if (l15 == 0) atomicAdd(&outp[row], s);
        }
    }
}

__global__ void k_gates(const float* __restrict__ gi, const float* __restrict__ gh,
                        const float* __restrict__ h, float* __restrict__ hnext) {
    int i = blockIdx.x * 256 + threadIdx.x;
    int b = i >> 9, k = i & 511;
    float ir = gi[b * H3 + k], iz = gi[b * H3 + H + k], inn = gi[b * H3 + 2 * H + k];
    float hr = gh[b * H3 + k], hz = gh[b * H3 + H + k], hn = gh[b * H3 + 2 * H + k];
    float r = 1.f / (1.f + __expf(-(ir + hr)));
    float z = 1.f / (1.f + __expf(-(iz + hz)));
    float n = fast_tanh(inn + r * hn);
    hnext[i] = (1.f - z) * n + z * h[i];
}

// fused: blocks [0,B) word masked-softmax+coverage; [B,2B) sent softmax+ctx
__global__ __launch_bounds__(256) void k_smax_sent(
        const float* __restrict__ wscore, const float* __restrict__ wmask,
        const float* __restrict__ cov, float* __restrict__ wattn, float* __restrict__ wcov,
        const float* __restrict__ sscore, const float* __restrict__ smask,
        const float* __restrict__ smb, float* __restrict__ sctx) {
    __shared__ float sc[L];
    __shared__ float red[4];
    int t = threadIdx.x;
    if (blockIdx.x < B) {
        int b = blockIdx.x;
        float mx = -1e30f;
        for (int l = t; l < L; l += 256) { float s = wscore[b * L + l]; sc[l] = s; mx = fmaxf(mx, s); }
        for (int off = 32; off; off >>= 1) mx = fmaxf(mx, __shfl_xor(mx, off));
        if ((t & 63) == 0) red[t >> 6] = mx;
        __syncthreads();
        mx = fmaxf(fmaxf(red[0], red[1]), fmaxf(red[2], red[3]));
        __syncthreads();
        float sm = 0.f;
        for (int l = t; l < L; l += 256) { float e = __expf(sc[l] - mx); sc[l] = e; sm += e; }
        for (int off = 32; off; off >>= 1) sm += __shfl_xor(sm, off);
        if ((t & 63) == 0) red[t >> 6] = sm;
        __syncthreads();
        float Z = red[0] + red[1] + red[2] + red[3];
        __syncthreads();
        float sm2 = 0.f;
        for (int l = t; l < L; l += 256) {
            float a = (sc[l] / Z) * wmask[b * L + l];
            sc[l] = a; sm2 += a;
        }
        for (int off = 32; off; off >>= 1) sm2 += __shfl_xor(sm2, off);
        if ((t & 63) == 0) red[t >> 6] = sm2;
        __syncthreads();
        float Zm = red[0] + red[1] + red[2] + red[3] + 1e-10f;
        for (int l = t; l < L; l += 256) {
            float a = sc[l] / Zm;
            wattn[b * L + l] = a;
            wcov[b * L + l] = cov[b * L + l] + a;
        }
    } else {
        int b = blockIdx.x - B;
        float* sa = sc; float* sa2 = sc + 32; float* smk = sc + 64;
        if (t < S) { sa[t] = sscore[b * S + t]; smk[t] = smask[b * S + t]; }
        __syncthreads();
        if (t < S) {
            float mx = -1e30f;
            for (int l = 0; l < S; ++l) mx = fmaxf(mx, sa[l]);
            float Z = 0.f, Zm = 0.f;
            for (int l = 0; l < S; ++l) { float e = __expf(sa[l] - mx); Z += e; Zm += e * smk[l]; }
            float e = __expf(sa[t] - mx);
            float a = (e / Z) * smk[t];
            sa2[t] = a / (Zm / Z + 1e-10f);
        }
        __syncthreads();
        float a0 = 0.f, a1 = 0.f;
        for (int l = 0; l < S; ++l) {
            const float* r = smb + ((size_t)b * S + l) * M;
            float a = sa2[l];
            a0 += a * r[t]; a1 += a * r[t + 256];
        }
        sctx[b * M + t] = a0; sctx[b * M + t + 256] = a1;
    }
}

// ctx partials: grid (4, B)
__global__ __launch_bounds__(256) void k_ctx_part(
        const float* __restrict__ attn, const float* __restrict__ memb,
        float* __restrict__ ctxp) {
    __shared__ float sa[100];
    int b = blockIdx.y, ch = blockIdx.x, t = threadIdx.x;
    int l0 = ch * 100;
    if (t < 100) sa[t] = attn[b * L + l0 + t];
    __syncthreads();
    float ax = 0.f, ay = 0.f;
    const float* base = memb + ((size_t)b * L + l0) * M + t * 2;
#pragma unroll 4
    for (int l = 0; l < 100; ++l) {
        float2 m2 = *(const float2*)(base + (size_t)l * M);
        float a = sa[l];
        ax += a * m2.x; ay += a * m2.y;
    }
    float* o = ctxp + ((size_t)(ch * B + b)) * M + t * 2;
    o[0] = ax; o[1] = ay;
}

// fused: [0,256) ctx reduce -> wctx + cat[:,0:512]; [256,768) cat[:,512:1536]; [768,768+B) p_gen
__global__ void k_ctxcat(const float* __restrict__ ctxp, const float* __restrict__ sctx,
                         const float* __restrict__ hnext, const float* __restrict__ yemb,
                         const float* __restrict__ pw, const float* __restrict__ pb,
                         float* __restrict__ wctx, float* __restrict__ cat,
                         float* __restrict__ pg) {
    int bb = blockIdx.x, t = threadIdx.x;
    if (bb < 256) {
        int j = bb * 256 + t;  // B*M
        float v = ctxp[j] + ctxp[B * M + j] + ctxp[2 * B * M + j] + ctxp[3 * B * M + j];
        wctx[j] = v;
        int b = j >> 9, c = j & 511;
        cat[b * H3 + c] = v;
    } else if (bb < 768) {
        int i = (bb - 256) * 256 + t;  // B*1024
        int b = i >> 10, c = i & 1023;
        cat[b * H3 + 512 + c] = (c < 512) ? sctx[b * 512 + c] : hnext[b * 512 + c - 512];
    } else {
        int b = bb - 768;
        if (t < 64) {
            float s = 0.f;
            for (int i = t; i < EMB + H + 2 * M; i += 64) {
                float x;
                if (i < 512) {
                    int j = b * 512 + i;
                    x = ctxp[j] + ctxp[B * M + j] + ctxp[2 * B * M + j] + ctxp[3 * B * M + j];
                } else if (i < 1024) x = sctx[b * 512 + i - 512];
                else if (i < 1536)   x = hnext[b * 512 + i - 1024];
                else                 x = yemb[b * EMB + i - 1536];
                s += x * pw[i];
            }
            for (int off = 32; off; off >>= 1) s += __shfl_xor(s, off);
            if (t == 0) pg[b] = 1.f / (1.f + __expf(-(s + pb[0])));
        }
    }
}

// vocab softmax partials: grid (10, B); chunk = 5000 cols
__global__ __launch_bounds__(256) void k_vpart(
        const float* __restrict__ logits, float* __restrict__ pm, float* __restrict__ ps) {
    __shared__ float wm[4], wsv[4];
    int b = blockIdx.y, c = blockIdx.x, t = threadIdx.x;
    const float4* row = (const float4*)(logits + (size_t)b * V) + c * 1250;
    float m = -3e38f, s = 0.f;
    for (int i = t; i < 1250; i += 256) {
        float4 x = row[i];
        float m4 = fmaxf(fmaxf(x.x, x.y), fmaxf(x.z, x.w));
        if (m4 > m) { s *= __expf(m - m4); m = m4; }
        s += __expf(x.x - m) + __expf(x.y - m) + __expf(x.z - m) + __expf(x.w - m);
    }
    for (int off = 32; off; off >>= 1) {
        float mo = __shfl_xor(m, off), so = __shfl_xor(s, off);
        float mn = fmaxf(m, mo);
        s = s * __expf(m - mn) + so * __expf(mo - mn);
        m = mn;
    }
    if ((t & 63) == 0) { wm[t >> 6] = m; wsv[t >> 6] = s; }
    __syncthreads();
    if (t == 0) {
        float M2 = fmaxf(fmaxf(wm[0], wm[1]), fmaxf(wm[2], wm[3]));
        float S2 = wsv[0] * __expf(wm[0] - M2) + wsv[1] * __expf(wm[1] - M2) +
                   wsv[2] * __expf(wm[2] - M2) + wsv[3] * __expf(wm[3] - M2);
        pm[b * 10 + c] = M2; ps[b * 10 + c] = S2;
    }
}

// final dist write: grid (25, B); 2048 cols per block
__global__ __launch_bounds__(256) void k_vwrite(
        const float* __restrict__ logits, const float* __restrict__ pm,
        const float* __restrict__ ps, const float* __restrict__ pgen,
        float* __restrict__ fd) {
    int b = blockIdx.y, t = threadIdx.x;
    float M2 = -3e38f;
#pragma unroll
    for (int c = 0; c < 10; ++c) M2 = fmaxf(M2, pm[b * 10 + c]);
    float S2 = 0.f;
#pragma unroll
    for (int c = 0; c < 10; ++c) S2 += ps[b * 10 + c] * __expf(pm[b * 10 + c] - M2);
    float inv = pgen[b] / S2;
    int col0 = blockIdx.x * 2048 + t * 8;
    float* outb = fd + (size_t)b * VO;
    if (col0 + 8 <= V) {
        const float4* lp = (const float4*)(logits + (size_t)b * V + col0);
        float4 x = lp[0], z = lp[1];
        *(float2*)(outb + col0)     = make_float2(inv * __expf(x.x - M2), inv * __expf(x.y - M2));
        *(float2*)(outb + col0 + 2) = make_float2(inv * __expf(x.z - M2), inv * __expf(x.w - M2));
        *(float2*)(outb + col0 + 4) = make_float2(inv * __expf(z.x - M2), inv * __expf(z.y - M2));
        *(float2*)(outb + col0 + 6) = make_float2(inv * __expf(z.z - M2), inv * __expf(z.w - M2));
    } else {
#pragma unroll
        for (int k = 0; k < 8; k += 2) {
            int c = col0 + k;
            if (c + 2 <= VO) {
                float2 o;
                o.x = (c < V)     ? inv * __expf(logits[(size_t)b * V + c] - M2) : 0.f;
                o.y = (c + 1 < V) ? inv * __expf(logits[(size_t)b * V + c + 1] - M2) : 0.f;
                *(float2*)(outb + c) = o;
            }
        }
    }
}

__global__ void k_scatter(const int* __restrict__ oov, const float* __restrict__ wattn,
                          const float* __restrict__ pgen, float* __restrict__ fd) {
    int i = blockIdx.x * 256 + threadIdx.x;
    int b = i / L;
    float w = (1.f - pgen[b]) * wattn[i];
    atomicAdd(&fd[(size_t)b * VO + oov[i]], w);
}

extern "C" void kernel_launch(void* const* d_in, const int* in_sizes, int n_in,
                              void* d_out, int out_size, void* d_ws, size_t ws_size,
                              hipStream_t stream) {
    const float* h     = (const float*)d_in[0];
    const float* wmb   = (const float*)d_in[1];
    const float* smb   = (const float*)d_in[2];
    const float* wmask = (const float*)d_in[3];
    const float* smask = (const float*)d_in[4];
    const float* cov   = (const float*)d_in[5];
    const float* emb   = (const float*)d_in[6];
    const float* Wih   = (const float*)d_in[7];
    const float* Whh   = (const float*)d_in[8];
    const float* bih   = (const float*)d_in[9];
    const float* bhh   = (const float*)d_in[10];
    const float* Wmpw  = (const float*)d_in[11];
    const float* Wdpw  = (const float*)d_in[12];
    const float* bdpw  = (const float*)d_in[13];
    const float* vw    = (const float*)d_in[14];
    const float* covp  = (const float*)d_in[15];
    const float* Wmps  = (const float*)d_in[16];
    const float* Wdps  = (const float*)d_in[17];
    const float* bdps  = (const float*)d_in[18];
    const float* vs    = (const float*)d_in[19];
    const float* pw    = (const float*)d_in[20];
    const float* pb    = (const float*)d_in[21];
    const float* vd1w  = (const float*)d_in[22];
    const float* vd1b  = (const float*)d_in[23];
    const float* vd2w  = (const float*)d_in[24];
    const float* vd2b  = (const float*)d_in[25];
    const int*   y     = (const int*)d_in[26];
    const int*   oov   = (const int*)d_in[27];

    float* out   = (float*)d_out;
    float* fd    = out;
    float* hnext = out + O_HN;
    float* wctx  = out + O_WCTX;
    float* wattn = out + O_WATTN;
    float* pgen  = out + O_PGEN;
    float* wcov  = out + O_WCOV;

    float* ws     = (float*)d_ws;
    float* yemb   = ws;
    float* gi     = yemb + B * EMB;
    float* gh     = gi + B * H3;
    float* dpw    = gh + B * H3;
    float* dps    = dpw + B * H;
    float* wscore = dps + B * H;
    float* sscore = wscore + B * L;
    float* sctx   = sscore + B * S;
    float* hid    = sctx + B * M;
    float* logits = hid + B * H;
    float* cat    = gi;      // gi consumed by k_gates before cat is written
    float* ctxp   = logits;  // ctxp consumed by k_ctxcat before logits written
    short* wb     = (short*)(logits + (size_t)B * V);
    short* wb_ih  = wb;
    short* wb_hh  = wb_ih + H3 * EMB;
    short* wb_dpw = wb_hh + H3 * H;
    short* wb_dps = wb_dpw + H * H;
    short* wb_mpw = wb_dps + H * H;
    short* wb_mps = wb_mpw + H * M;
    short* wb_v1  = wb_mps + H * M;
    float* pm     = (float*)(wb_v1 + H * H3);
    float* psum   = pm + B * 10;

    k_setup<<<2583 + 1376, 256, 0, stream>>>(bih, bhh, bdpw, bdps, vd1b, emb, y,
                                             gi, gh, dpw, dps, hid, wscore, sscore, yemb,
                                             Wih, Whh, Wdpw, Wdps, Wmpw, Wmps, vd1w,
                                             wb_ih, wb_hh, wb_dpw, wb_dps, wb_mpw, wb_mps, wb_v1);
    // gi += yemb@Wih^T (12 tiles, K=128) ; gh += h@Whh^T (12 tiles, K=512, ksplit 2)
    k_mmsk<<<36, 256, 0, stream>>>(yemb, wb_ih, gi, 128, 12, 1,
                                   h, wb_hh, gh, 512, 12, 2);
    k_gates<<<256, 256, 0, stream>>>(gi, gh, h, hnext);
    // dpw, dps: each 4 tiles, K=512, ksplit 2
    k_mmsk<<<16, 256, 0, stream>>>(hnext, wb_dpw, dpw, 512, 4, 2,
                                   hnext, wb_dps, dps, 512, 4, 2);
    k_feat<<<dim3(4, 430), 256, 0, stream>>>(wmb, wb_mpw, dpw, cov, covp, vw, wscore,
                                             smb, wb_mps, dps, vs, sscore);
    k_smax_sent<<<2 * B, 256, 0, stream>>>(wscore, wmask, cov, wattn, wcov,
                                           sscore, smask, smb, sctx);
    k_ctx_part<<<dim3(4, B), 256, 0, stream>>>(wattn, wmb, ctxp);
    k_ctxcat<<<768 + B, 256, 0, stream>>>(ctxp, sctx, hnext, yemb, pw, pb,
                                          wctx, cat, pgen);
    // hid += cat@vd1w^T (4 tiles, K=1536, ksplit 6)
    k_mmsk<<<24, 256, 0, stream>>>(cat, wb_v1, hid, 1536, 4, 6,
                                   nullptr, nullptr, nullptr, 64, 1, 0);
    k_mm128<<<(V + 127) / 128, 256, 0, stream>>>(hid, vd2w, vd2b, logits, H, V, V);
    k_vpart<<<dim3(10, B), 256, 0, stream>>>(logits, pm, psum);
    k_vwrite<<<dim3(25, B), 256, 0, stream>>>(logits, pm, psum, pgen, fd);
    k_scatter<<<200, 256, 0, stream>>>(oov, wattn, pgen, fd);
}

// Round 7
// 232.842 us; speedup vs baseline: 1.1380x; 1.1380x over previous
//
#include <hip/hip_runtime.h>
#include <hip/hip_bf16.h>
#include <math.h>

#define B 128
#define L 400
#define S 30
#define V 50000
#define EMB 128
#define H 512
#define M 512
#define OOV 30
#define H3 1536
#define VO (V + OOV)

// ---- output layout (floats) ----
#define O_HN    (B * VO)
#define O_WCTX  (O_HN + B * H)
#define O_WATTN (O_WCTX + B * M)
#define O_PGEN  (O_WATTN + B * L)
#define O_WCOV  (O_PGEN + B)

typedef short bf16x8 __attribute__((ext_vector_type(8)));
typedef float f32x4 __attribute__((ext_vector_type(4)));

__device__ __forceinline__ unsigned pk2(float a, float b) {
    union { __hip_bfloat162 h; unsigned u; } cv;
    cv.h = __float22bfloat162_rn(make_float2(a, b));
    return cv.u;
}

__device__ __forceinline__ float fast_tanh(float x) {
    float e = __expf(2.f * x);
    return 1.f - 2.f * __builtin_amdgcn_rcpf(e + 1.f);
}

// async global->LDS, 16B per lane; lds ptr must be wave-uniform (HW adds lane*16)
__device__ __forceinline__ void gload16(const void* g, void* l) {
    __builtin_amdgcn_global_load_lds(
        (const __attribute__((address_space(1))) unsigned int*)g,
        (__attribute__((address_space(3))) unsigned int*)l, 16, 0, 0);
}

// ---- fused setup: bias-broadcast C buffers, zero scores, y-emb gather, weight cvt ----
__global__ void k_setup(const float* __restrict__ bih, const float* __restrict__ bhh,
                        const float* __restrict__ bdpw, const float* __restrict__ bdps,
                        const float* __restrict__ v1b, const float* __restrict__ emb,
                        const int* __restrict__ y,
                        float* gi, float* gh, float* dpw, float* dps, float* hid,
                        float* wscore, float* sscore, float* yemb,
                        const float* __restrict__ wih, const float* __restrict__ whh,
                        const float* __restrict__ wdpw, const float* __restrict__ wdps,
                        const float* __restrict__ wmpw, const float* __restrict__ wmps,
                        const float* __restrict__ v1,
                        short* o_ih, short* o_hh, short* o_dpw, short* o_dps,
                        short* o_mpw, short* o_mps, short* o_v1) {
    int bb = blockIdx.x;
    if (bb < 2583) {
        int i = bb * 256 + threadIdx.x;
        if (i < 196608) { gi[i] = bih[i % 1536]; return; }
        i -= 196608;
        if (i < 196608) { gh[i] = bhh[i % 1536]; return; }
        i -= 196608;
        if (i < 65536) { dpw[i] = bdpw[i & 511]; return; }
        i -= 65536;
        if (i < 65536) { dps[i] = bdps[i & 511]; return; }
        i -= 65536;
        if (i < 65536) { hid[i] = v1b[i & 511]; return; }
        i -= 65536;
        if (i < 51200) { wscore[i] = 0.f; return; }
        i -= 51200;
        if (i < 3840) { sscore[i] = 0.f; return; }
        i -= 3840;
        if (i < 16384) { int b = i >> 7, e = i & 127; yemb[i] = emb[(size_t)y[b] * EMB + e]; }
        return;
    }
    bb -= 2583;
    const float* src; short* dst;
    if      (bb < 96)  { src = wih;  dst = o_ih; }
    else if (bb < 480) { src = whh;  dst = o_hh;  bb -= 96; }
    else if (bb < 608) { src = wdpw; dst = o_dpw; bb -= 480; }
    else if (bb < 736) { src = wdps; dst = o_dps; bb -= 608; }
    else if (bb < 864) { src = wmpw; dst = o_mpw; bb -= 736; }
    else if (bb < 992) { src = wmps; dst = o_mps; bb -= 864; }
    else               { src = v1;   dst = o_v1;  bb -= 992; }
    size_t i = (size_t)bb * 2048 + threadIdx.x * 8;
    float4 a = *(const float4*)(src + i);
    float4 c = *(const float4*)(src + i + 4);
    uint4 w;
    w.x = pk2(a.x, a.y); w.y = pk2(a.z, a.w);
    w.z = pk2(c.x, c.y); w.w = pk2(c.z, c.w);
    *(uint4*)(dst + i) = w;
}

// convert one 16B granule into tiled+swizzled bf16 layout.
// dst block (tile,kc): TR rows x 64 cols; granule (r,g) holds src cols (g^(r&7))*8..+8
__device__ __forceinline__ void cvt_granule(const float* __restrict__ src,
                                            short* __restrict__ dst,
                                            int gidx, int TRlog) {
    int TR = 1 << TRlog;
    int g = gidx & 7;
    int r = (gidx >> 3) & (TR - 1);
    int kc = (gidx >> (3 + TRlog)) & 7;
    int tile = gidx >> (6 + TRlog);
    const float* p = src + (size_t)(tile * TR + r) * 512 + kc * 64 + ((g ^ (r & 7)) << 3);
    float4 a = *(const float4*)p;
    float4 c = *(const float4*)(p + 4);
    uint4 w;
    w.x = pk2(a.x, a.y); w.y = pk2(a.z, a.w);
    w.z = pk2(c.x, c.y); w.w = pk2(c.z, c.w);
    *(uint4*)(dst + (size_t)gidx * 8) = w;
}

// stage 128 rows x 64 cols fp32 -> bf16 LDS [128][72]  (fallback path)
__device__ __forceinline__ void stage_a(const float* __restrict__ src, int SK, int rmax,
                                        int t, short dst[128][72]) {
    int col = (t & 7) * 8;
    int r0 = t >> 3;
#pragma unroll
    for (int i = 0; i < 4; ++i) {
        int r = r0 + i * 32;
        int rr = r < rmax ? r : rmax;
        const float* p = src + (size_t)rr * SK + col;
        float4 a = *(const float4*)p;
        float4 c = *(const float4*)(p + 4);
        uint4 w;
        w.x = pk2(a.x, a.y); w.y = pk2(a.z, a.w);
        w.z = pk2(c.x, c.y); w.w = pk2(c.z, c.w);
        *(uint4*)&dst[r][col] = w;
    }
}

__device__ __forceinline__ void stage_b128bf(const short* __restrict__ src, int K,
                                             int t, short dst[128][72]) {
    int col = (t & 7) * 8;
    int r0 = t >> 3;
#pragma unroll
    for (int i = 0; i < 4; ++i) {
        int r = r0 + i * 32;
        *(bf16x8*)&dst[r][col] = *(const bf16x8*)(src + (size_t)r * K + col);
    }
}

__device__ __forceinline__ void stage_b256bf(const short* __restrict__ src, int K,
                                             int t, short dst[256][72]) {
    int col = (t & 7) * 8;
    int r0 = t >> 3;
#pragma unroll
    for (int i = 0; i < 8; ++i) {
        int r = r0 + i * 32;
        *(bf16x8*)&dst[r][col] = *(const bf16x8*)(src + (size_t)r * K + col);
    }
}

// ---------- split-K skinny GEMM (M=128) + fused tiled-bf16 conversion tail ----------
__global__ __launch_bounds__(256, 2) void k_mmsk(
        const float* __restrict__ A0, const short* __restrict__ B0, float* __restrict__ C0,
        int K0, int NT0, int KB0,
        const float* __restrict__ A1, const short* __restrict__ B1, float* __restrict__ C1,
        int K1, int NT1, int KB1,
        int gemmBlocks,
        const float* __restrict__ cs0, short* __restrict__ cd0, int ntile0,
        const float* __restrict__ cs1, short* __restrict__ cd1, int TRlog) {
    __shared__ short As[128][72];
    __shared__ short Bs[128][72];
    int t = threadIdx.x;
    if ((int)blockIdx.x >= gemmBlocks) {
        int gidx = ((int)blockIdx.x - gemmBlocks) * 256 + t;
        int split = ntile0 * (64 << TRlog);
        if (gidx < split) cvt_granule(cs0, cd0, gidx, TRlog);
        else              cvt_granule(cs1, cd1, gidx - split, TRlog);
        return;
    }
    int lane = t & 63, wv = t >> 6;
    int wr = wv >> 1, wc = wv & 1;
    int l15 = lane & 15, l4 = lane >> 4;

    int bb = blockIdx.x;
    const float* A; const short* Bb; float* C; int K, NT, KB;
    if (bb < NT0 * KB0) { A = A0; Bb = B0; C = C0; K = K0; NT = NT0; KB = KB0; }
    else { bb -= NT0 * KB0; A = A1; Bb = B1; C = C1; K = K1; NT = NT1; KB = KB1; }
    int nIdx = bb % NT, kIdx = bb / NT;
    int ldc = NT * 128;
    int nBase = nIdx * 128;
    int KC = K / KB;
    int kLo = kIdx * KC, kHi = kLo + KC;

    f32x4 acc[4][4] = {};
    for (int kc = kLo; kc < kHi; kc += 64) {
        stage_a(A + kc, K, 127, t, As);
        stage_b128bf(Bb + (size_t)nBase * K + kc, K, t, Bs);
        __syncthreads();
#pragma unroll
        for (int kk = 0; kk < 2; ++kk) {
            bf16x8 af[4], bq[4];
#pragma unroll
            for (int i = 0; i < 4; ++i)
                af[i] = *(const bf16x8*)&As[wr * 64 + i * 16 + l15][kk * 32 + l4 * 8];
#pragma unroll
            for (int j = 0; j < 4; ++j)
                bq[j] = *(const bf16x8*)&Bs[wc * 64 + j * 16 + l15][kk * 32 + l4 * 8];
#pragma unroll
            for (int i = 0; i < 4; ++i)
#pragma unroll
                for (int j = 0; j < 4; ++j)
                    acc[i][j] = __builtin_amdgcn_mfma_f32_16x16x32_bf16(
                        af[i], bq[j], acc[i][j], 0, 0, 0);
        }
        __syncthreads();
    }
#pragma unroll
    for (int i = 0; i < 4; ++i)
#pragma unroll
        for (int r = 0; r < 4; ++r) {
            int row = wr * 64 + i * 16 + l4 * 4 + r;
#pragma unroll
            for (int j = 0; j < 4; ++j) {
                int n = nBase + wc * 64 + j * 16 + l15;
                atomicAdd(&C[(size_t)row * ldc + n], acc[i][j][r]);
            }
        }
}

// ---------- vocab logits GEMM: C[128,V] = hid @ vd2w^T + bias ----------
__global__ __launch_bounds__(256, 4) void k_mm128(
        const float* __restrict__ Ap, const float* __restrict__ Bf,
        const float* __restrict__ bias, float* __restrict__ C, int K, int ldc, int Nlim) {
    __shared__ short As[128][72];
    __shared__ short Bs[128][72];
    int t = threadIdx.x, lane = t & 63, wv = t >> 6;
    int wr = wv >> 1, wc = wv & 1;
    int l15 = lane & 15, l4 = lane >> 4;
    int nBase = blockIdx.x * 128;
    int brmax = Nlim - 1 - nBase; if (brmax > 127) brmax = 127;

    f32x4 acc[4][4] = {};
    for (int kc = 0; kc < K; kc += 64) {
        stage_a(Ap + kc, K, 127, t, As);
        stage_a(Bf + (size_t)nBase * K + kc, K, brmax, t, Bs);
        __syncthreads();
#pragma unroll
        for (int kk = 0; kk < 2; ++kk) {
            bf16x8 af[4], bq[4];
#pragma unroll
            for (int i = 0; i < 4; ++i)
                af[i] = *(const bf16x8*)&As[wr * 64 + i * 16 + l15][kk * 32 + l4 * 8];
#pragma unroll
            for (int j = 0; j < 4; ++j)
                bq[j] = *(const bf16x8*)&Bs[wc * 64 + j * 16 + l15][kk * 32 + l4 * 8];
#pragma unroll
            for (int i = 0; i < 4; ++i)
#pragma unroll
                for (int j = 0; j < 4; ++j)
                    acc[i][j] = __builtin_amdgcn_mfma_f32_16x16x32_bf16(
                        af[i], bq[j], acc[i][j], 0, 0, 0);
        }
        __syncthreads();
    }
#pragma unroll
    for (int i = 0; i < 4; ++i)
#pragma unroll
        for (int r = 0; r < 4; ++r) {
            int row = wr * 64 + i * 16 + l4 * 4 + r;
#pragma unroll
            for (int j = 0; j < 4; ++j) {
                int n = nBase + wc * 64 + j * 16 + l15;
                if (n < Nlim) C[(size_t)row * ldc + n] = acc[i][j][r] + bias[n];
            }
        }
}

// ---------- PRIMARY feat: tiled-bf16 + global_load_lds + swizzled ds_read ----------
// tile 128 rows x 256 d-cols, K=512; grid (2, 430)
__global__ __launch_bounds__(256, 2) void k_feat_g(
        const short* __restrict__ wmb_t, const short* __restrict__ wmp_t,
        const float* __restrict__ dpw, const float* __restrict__ cov,
        const float* __restrict__ covp, const float* __restrict__ vw,
        float* __restrict__ wscore,
        const short* __restrict__ smb_t, const short* __restrict__ smp_t,
        const float* __restrict__ dps, const float* __restrict__ vs,
        float* __restrict__ sscore) {
    __shared__ alignas(16) short As[128 * 64];
    __shared__ alignas(16) short Bs[256 * 64];
    int t = threadIdx.x, lane = t & 63, wv = t >> 6;
    int wr = wv >> 1, wc = wv & 1;
    int l15 = lane & 15, l4 = lane >> 4;

    bool word = blockIdx.y < 400;
    const short* At; const short* Bt; const float* dproj; const float* vvec; float* outp;
    int tile;
    if (word) { At = wmb_t; Bt = wmp_t; dproj = dpw; vvec = vw; outp = wscore; tile = blockIdx.y; }
    else      { At = smb_t; Bt = smp_t; dproj = dps; vvec = vs; outp = sscore; tile = blockIdx.y - 400; }
    int rowBase = tile * 128;
    int nT = blockIdx.x;  // 0..1
    int nBase = nT * 256;
    const short* Abase = At + (size_t)tile * 65536;   // 8 kc * 8192 shorts
    const short* Bbase = Bt + (size_t)nT * 131072;    // 8 kc * 16384 shorts

    f32x4 acc[4][8] = {};
    int swz = l15 & 7;
    for (int kc = 0; kc < 8; ++kc) {
        const char* Ab = (const char*)(Abase + kc * 8192);
        const char* Bb = (const char*)(Bbase + kc * 16384);
        char* AsB = (char*)As;
        char* BsB = (char*)Bs;
#pragma unroll
        for (int it = 0; it < 4; ++it) {
            int lo = wv * 4096 + it * 1024;
            gload16(Ab + lo + lane * 16, AsB + lo);
        }
#pragma unroll
        for (int it = 0; it < 8; ++it) {
            int lo = wv * 8192 + it * 1024;
            gload16(Bb + lo + lane * 16, BsB + lo);
        }
        __syncthreads();
#pragma unroll
        for (int kk = 0; kk < 2; ++kk) {
            int g = ((kk * 4 + l4) ^ swz) * 8;
            bf16x8 af[4], bq[8];
#pragma unroll
            for (int i = 0; i < 4; ++i)
                af[i] = *(const bf16x8*)&As[(wr * 64 + i * 16 + l15) * 64 + g];
#pragma unroll
            for (int j = 0; j < 8; ++j)
                bq[j] = *(const bf16x8*)&Bs[(wc * 128 + j * 16 + l15) * 64 + g];
#pragma unroll
            for (int i = 0; i < 4; ++i)
#pragma unroll
                for (int j = 0; j < 8; ++j)
                    acc[i][j] = __builtin_amdgcn_mfma_f32_16x16x32_bf16(
                        af[i], bq[j], acc[i][j], 0, 0, 0);
        }
        __syncthreads();
    }
    int dB = nBase + wc * 128;
    float vv[8], cp[8], dp0[8], dp1[8];
    int b0 = word ? rowBase / 400 : 0;
    int b1 = word ? (rowBase + 127) / 400 : 0;
#pragma unroll
    for (int j = 0; j < 8; ++j) {
        int d = dB + j * 16 + l15;
        vv[j] = vvec[d];
        cp[j] = word ? covp[d] : 0.f;
        if (word) { dp0[j] = dproj[b0 * H + d]; dp1[j] = dproj[b1 * H + d]; }
    }
#pragma unroll
    for (int i = 0; i < 4; ++i) {
#pragma unroll
        for (int r = 0; r < 4; ++r) {
            int row = rowBase + wr * 64 + i * 16 + l4 * 4 + r;
            int b = word ? (row / 400) : (row / 30);
            float cv = word ? cov[row] : 0.f;
            bool use0 = (b == b0);
            float s = 0.f;
#pragma unroll
            for (int j = 0; j < 8; ++j) {
                float dpv = word ? (use0 ? dp0[j] : dp1[j])
                                 : dproj[b * H + dB + j * 16 + l15];
                float f = acc[i][j][r] + dpv + cv * cp[j];
                s += vv[j] * fast_tanh(f);
            }
            s += __shfl_xor(s, 8, 16);
            s += __shfl_xor(s, 4, 16);
            s += __shfl_xor(s, 2, 16);
            s += __shfl_xor(s, 1, 16);
            if (l15 == 0) atomicAdd(&outp[row], s);
        }
    }
}

// ---------- FALLBACK feat (fp32 A staging, row-major bf16 B) ----------
__global__ __launch_bounds__(256, 2) void k_feat2(
        const float* __restrict__ wmb, const short* __restrict__ wbmpw,
        const float* __restrict__ dpw, const float* __restrict__ cov,
        const float* __restrict__ covp, const float* __restrict__ vw,
        float* __restrict__ wscore,
        const float* __restrict__ smb, const short* __restrict__ wbmps,
        const float* __restrict__ dps, const float* __restrict__ vs,
        float* __restrict__ sscore) {
    __shared__ short As[128][72];
    __shared__ short Bs[256][72];
    int t = threadIdx.x, lane = t & 63, wv = t >> 6;
    int wr = wv >> 1, wc = wv & 1;
    int l15 = lane & 15, l4 = lane >> 4;

    bool word = blockIdx.y < 400;
    const float* Ap; const short* Bbf; const float* dproj; const float* vvec; float* outp;
    int rowBase;
    if (word) { Ap = wmb; Bbf = wbmpw; dproj = dpw; vvec = vw; outp = wscore; rowBase = blockIdx.y * 128; }
    else      { Ap = smb; Bbf = wbmps; dproj = dps; vvec = vs; outp = sscore; rowBase = (blockIdx.y - 400) * 128; }
    int nBase = blockIdx.x * 256;
    const float* Asrc = Ap + (size_t)rowBase * 512;
    const short* Bsrc = Bbf + (size_t)nBase * 512;

    f32x4 acc[4][8] = {};
    for (int kc = 0; kc < 512; kc += 64) {
        stage_a(Asrc + kc, 512, 127, t, As);
        stage_b256bf(Bsrc + kc, 512, t, Bs);
        __syncthreads();
#pragma unroll
        for (int kk = 0; kk < 2; ++kk) {
            bf16x8 af[4], bq[8];
#pragma unroll
            for (int i = 0; i < 4; ++i)
                af[i] = *(const bf16x8*)&As[wr * 64 + i * 16 + l15][kk * 32 + l4 * 8];
#pragma unroll
            for (int j = 0; j < 8; ++j)
                bq[j] = *(const bf16x8*)&Bs[wc * 128 + j * 16 + l15][kk * 32 + l4 * 8];
#pragma unroll
            for (int i = 0; i < 4; ++i)
#pragma unroll
                for (int j = 0; j < 8; ++j)
                    acc[i][j] = __builtin_amdgcn_mfma_f32_16x16x32_bf16(
                        af[i], bq[j], acc[i][j], 0, 0, 0);
        }
        __syncthreads();
    }
    int dB = nBase + wc * 128;
    float vv[8], cp[8], dp0[8], dp1[8];
    int b0 = word ? rowBase / 400 : 0;
    int b1 = word ? (rowBase + 127) / 400 : 0;
#pragma unroll
    for (int j = 0; j < 8; ++j) {
        int d = dB + j * 16 + l15;
        vv[j] = vvec[d];
        cp[j] = word ? covp[d] : 0.f;
        if (word) { dp0[j] = dproj[b0 * H + d]; dp1[j] = dproj[b1 * H + d]; }
    }
#pragma unroll
    for (int i = 0; i < 4; ++i) {
#pragma unroll
        for (int r = 0; r < 4; ++r) {
            int row = rowBase + wr * 64 + i * 16 + l4 * 4 + r;
            int b = word ? (row / 400) : (row / 30);
            float cv = word ? cov[row] : 0.f;
            bool use0 = (b == b0);
            float s = 0.f;
#pragma unroll
            for (int j = 0; j < 8; ++j) {
                float dpv = word ? (use0 ? dp0[j] : dp1[j])
                                 : dproj[b * H + dB + j * 16 + l15];
                float f = acc[i][j][r] + dpv + cv * cp[j];
                s += vv[j] * fast_tanh(f);
            }
            s += __shfl_xor(s, 8, 16);
            s += __shfl_xor(s, 4, 16);
            s += __shfl_xor(s, 2, 16);
            s += __shfl_xor(s, 1, 16);
            if (l15 == 0) atomicAdd(&outp[row], s);
        }
    }
}

__global__ void k_gates(const float* __restrict__ gi, const float* __restrict__ gh,
                        const float* __restrict__ h, float* __restrict__ hnext) {
    int i = blockIdx.x * 256 + threadIdx.x;
    int b = i >> 9, k = i & 511;
    float ir = gi[b * H3 + k], iz = gi[b * H3 + H + k], inn = gi[b * H3 + 2 * H + k];
    float hr = gh[b * H3 + k], hz = gh[b * H3 + H + k], hn = gh[b * H3 + 2 * H + k];
    float r = 1.f / (1.f + __expf(-(ir + hr)));
    float z = 1.f / (1.f + __expf(-(iz + hz)));
    float n = fast_tanh(inn + r * hn);
    hnext[i] = (1.f - z) * n + z * h[i];
}

// fused: blocks [0,B) word masked-softmax+coverage; [B,2B) sent softmax+ctx
__global__ __launch_bounds__(256) void k_smax_sent(
        const float* __restrict__ wscore, const float* __restrict__ wmask,
        const float* __restrict__ cov, float* __restrict__ wattn, float* __restrict__ wcov,
        const float* __restrict__ sscore, const float* __restrict__ smask,
        const float* __restrict__ smb, float* __restrict__ sctx) {
    __shared__ float sc[L];
    __shared__ float red[4];
    int t = threadIdx.x;
    if (blockIdx.x < B) {
        int b = blockIdx.x;
        float mx = -1e30f;
        for (int l = t; l < L; l += 256) { float s = wscore[b * L + l]; sc[l] = s; mx = fmaxf(mx, s); }
        for (int off = 32; off; off >>= 1) mx = fmaxf(mx, __shfl_xor(mx, off));
        if ((t & 63) == 0) red[t >> 6] = mx;
        __syncthreads();
        mx = fmaxf(fmaxf(red[0], red[1]), fmaxf(red[2], red[3]));
        __syncthreads();
        float sm = 0.f;
        for (int l = t; l < L; l += 256) { float e = __expf(sc[l] - mx); sc[l] = e; sm += e; }
        for (int off = 32; off; off >>= 1) sm += __shfl_xor(sm, off);
        if ((t & 63) == 0) red[t >> 6] = sm;
        __syncthreads();
        float Z = red[0] + red[1] + red[2] + red[3];
        __syncthreads();
        float sm2 = 0.f;
        for (int l = t; l < L; l += 256) {
            float a = (sc[l] / Z) * wmask[b * L + l];
            sc[l] = a; sm2 += a;
        }
        for (int off = 32; off; off >>= 1) sm2 += __shfl_xor(sm2, off);
        if ((t & 63) == 0) red[t >> 6] = sm2;
        __syncthreads();
        float Zm = red[0] + red[1] + red[2] + red[3] + 1e-10f;
        for (int l = t; l < L; l += 256) {
            float a = sc[l] / Zm;
            wattn[b * L + l] = a;
            wcov[b * L + l] = cov[b * L + l] + a;
        }
    } else {
        int b = blockIdx.x - B;
        float* sa = sc; float* sa2 = sc + 32; float* smk = sc + 64;
        if (t < S) { sa[t] = sscore[b * S + t]; smk[t] = smask[b * S + t]; }
        __syncthreads();
        if (t < S) {
            float mx = -1e30f;
            for (int l = 0; l < S; ++l) mx = fmaxf(mx, sa[l]);
            float Z = 0.f, Zm = 0.f;
            for (int l = 0; l < S; ++l) { float e = __expf(sa[l] - mx); Z += e; Zm += e * smk[l]; }
            float e = __expf(sa[t] - mx);
            float a = (e / Z) * smk[t];
            sa2[t] = a / (Zm / Z + 1e-10f);
        }
        __syncthreads();
        float a0 = 0.f, a1 = 0.f;
        for (int l = 0; l < S; ++l) {
            const float* r = smb + ((size_t)b * S + l) * M;
            float a = sa2[l];
            a0 += a * r[t]; a1 += a * r[t + 256];
        }
        sctx[b * M + t] = a0; sctx[b * M + t + 256] = a1;
    }
}

// ctx partials: grid (4, B)
__global__ __launch_bounds__(256) void k_ctx_part(
        const float* __restrict__ attn, const float* __restrict__ memb,
        float* __restrict__ ctxp) {
    __shared__ float sa[100];
    int b = blockIdx.y, ch = blockIdx.x, t = threadIdx.x;
    int l0 = ch * 100;
    if (t < 100) sa[t] = attn[b * L + l0 + t];
    __syncthreads();
    float ax = 0.f, ay = 0.f;
    const float* base = memb + ((size_t)b * L + l0) * M + t * 2;
#pragma unroll 4
    for (int l = 0; l < 100; ++l) {
        float2 m2 = *(const float2*)(base + (size_t)l * M);
        float a = sa[l];
        ax += a * m2.x; ay += a * m2.y;
    }
    float* o = ctxp + ((size_t)(ch * B + b)) * M + t * 2;
    o[0] = ax; o[1] = ay;
}

// fused: [0,256) ctx reduce -> wctx + cat[:,0:512]; [256,768) cat[:,512:1536]; [768,768+B) p_gen
__global__ void k_ctxcat(const float* __restrict__ ctxp, const float* __restrict__ sctx,
                         const float* __restrict__ hnext, const float* __restrict__ yemb,
                         const float* __restrict__ pw, const float* __restrict__ pb,
                         float* __restrict__ wctx, float* __restrict__ cat,
                         float* __restrict__ pg) {
    int bb = blockIdx.x, t = threadIdx.x;
    if (bb < 256) {
        int j = bb * 256 + t;  // B*M
        float v = ctxp[j] + ctxp[B * M + j] + ctxp[2 * B * M + j] + ctxp[3 * B * M + j];
        wctx[j] = v;
        int b = j >> 9, c = j & 511;
        cat[b * H3 + c] = v;
    } else if (bb < 768) {
        int i = (bb - 256) * 256 + t;  // B*1024
        int b = i >> 10, c = i & 1023;
        cat[b * H3 + 512 + c] = (c < 512) ? sctx[b * 512 + c] : hnext[b * 512 + c - 512];
    } else {
        int b = bb - 768;
        if (t < 64) {
            float s = 0.f;
            for (int i = t; i < EMB + H + 2 * M; i += 64) {
                float x;
                if (i < 512) {
                    int j = b * 512 + i;
                    x = ctxp[j] + ctxp[B * M + j] + ctxp[2 * B * M + j] + ctxp[3 * B * M + j];
                } else if (i < 1024) x = sctx[b * 512 + i - 512];
                else if (i < 1536)   x = hnext[b * 512 + i - 1024];
                else                 x = yemb[b * EMB + i - 1536];
                s += x * pw[i];
            }
            for (int off = 32; off; off >>= 1) s += __shfl_xor(s, off);
            if (t == 0) pg[b] = 1.f / (1.f + __expf(-(s + pb[0])));
        }
    }
}

// vocab softmax partials: grid (10, B); chunk = 5000 cols
__global__ __launch_bounds__(256) void k_vpart(
        const float* __restrict__ logits, float* __restrict__ pm, float* __restrict__ ps) {
    __shared__ float wm[4], wsv[4];
    int b = blockIdx.y, c = blockIdx.x, t = threadIdx.x;
    const float4* row = (const float4*)(logits + (size_t)b * V) + c * 1250;
    float m = -3e38f, s = 0.f;
    for (int i = t; i < 1250; i += 256) {
        float4 x = row[i];
        float m4 = fmaxf(fmaxf(x.x, x.y), fmaxf(x.z, x.w));
        if (m4 > m) { s *= __expf(m - m4); m = m4; }
        s += __expf(x.x - m) + __expf(x.y - m) + __expf(x.z - m) + __expf(x.w - m);
    }
    for (int off = 32; off; off >>= 1) {
        float mo = __shfl_xor(m, off), so = __shfl_xor(s, off);
        float mn = fmaxf(m, mo);
        s = s * __expf(m - mn) + so * __expf(mo - mn);
        m = mn;
    }
    if ((t & 63) == 0) { wm[t >> 6] = m; wsv[t >> 6] = s; }
    __syncthreads();
    if (t == 0) {
        float M2 = fmaxf(fmaxf(wm[0], wm[1]), fmaxf(wm[2], wm[3]));
        float S2 = wsv[0] * __expf(wm[0] - M2) + wsv[1] * __expf(wm[1] - M2) +
                   wsv[2] * __expf(wm[2] - M2) + wsv[3] * __expf(wm[3] - M2);
        pm[b * 10 + c] = M2; ps[b * 10 + c] = S2;
    }
}

// final dist write: grid (25, B); 2048 cols per block
__global__ __launch_bounds__(256) void k_vwrite(
        const float* __restrict__ logits, const float* __restrict__ pm,
        const float* __restrict__ ps, const float* __restrict__ pgen,
        float* __restrict__ fd) {
    int b = blockIdx.y, t = threadIdx.x;
    float M2 = -3e38f;
#pragma unroll
    for (int c = 0; c < 10; ++c) M2 = fmaxf(M2, pm[b * 10 + c]);
    float S2 = 0.f;
#pragma unroll
    for (int c = 0; c < 10; ++c) S2 += ps[b * 10 + c] * __expf(pm[b * 10 + c] - M2);
    float inv = pgen[b] / S2;
    int col0 = blockIdx.x * 2048 + t * 8;
    float* outb = fd + (size_t)b * VO;
    if (col0 + 8 <= V) {
        const float4* lp = (const float4*)(logits + (size_t)b * V + col0);
        float4 x = lp[0], z = lp[1];
        *(float2*)(outb + col0)     = make_float2(inv * __expf(x.x - M2), inv * __expf(x.y - M2));
        *(float2*)(outb + col0 + 2) = make_float2(inv * __expf(x.z - M2), inv * __expf(x.w - M2));
        *(float2*)(outb + col0 + 4) = make_float2(inv * __expf(z.x - M2), inv * __expf(z.y - M2));
        *(float2*)(outb + col0 + 6) = make_float2(inv * __expf(z.z - M2), inv * __expf(z.w - M2));
    } else {
#pragma unroll
        for (int k = 0; k < 8; k += 2) {
            int c = col0 + k;
            if (c + 2 <= VO) {
                float2 o;
                o.x = (c < V)     ? inv * __expf(logits[(size_t)b * V + c] - M2) : 0.f;
                o.y = (c + 1 < V) ? inv * __expf(logits[(size_t)b * V + c + 1] - M2) : 0.f;
                *(float2*)(outb + c) = o;
            }
        }
    }
}

__global__ void k_scatter(const int* __restrict__ oov, const float* __restrict__ wattn,
                          const float* __restrict__ pgen, float* __restrict__ fd) {
    int i = blockIdx.x * 256 + threadIdx.x;
    int b = i / L;
    float w = (1.f - pgen[b]) * wattn[i];
    atomicAdd(&fd[(size_t)b * VO + oov[i]], w);
}

extern "C" void kernel_launch(void* const* d_in, const int* in_sizes, int n_in,
                              void* d_out, int out_size, void* d_ws, size_t ws_size,
                              hipStream_t stream) {
    const float* h     = (const float*)d_in[0];
    const float* wmb   = (const float*)d_in[1];
    const float* smb   = (const float*)d_in[2];
    const float* wmask = (const float*)d_in[3];
    const float* smask = (const float*)d_in[4];
    const float* cov   = (const float*)d_in[5];
    const float* emb   = (const float*)d_in[6];
    const float* Wih   = (const float*)d_in[7];
    const float* Whh   = (const float*)d_in[8];
    const float* bih   = (const float*)d_in[9];
    const float* bhh   = (const float*)d_in[10];
    const float* Wmpw  = (const float*)d_in[11];
    const float* Wdpw  = (const float*)d_in[12];
    const float* bdpw  = (const float*)d_in[13];
    const float* vw    = (const float*)d_in[14];
    const float* covp  = (const float*)d_in[15];
    const float* Wmps  = (const float*)d_in[16];
    const float* Wdps  = (const float*)d_in[17];
    const float* bdps  = (const float*)d_in[18];
    const float* vs    = (const float*)d_in[19];
    const float* pw    = (const float*)d_in[20];
    const float* pb    = (const float*)d_in[21];
    const float* vd1w  = (const float*)d_in[22];
    const float* vd1b  = (const float*)d_in[23];
    const float* vd2w  = (const float*)d_in[24];
    const float* vd2b  = (const float*)d_in[25];
    const int*   y     = (const int*)d_in[26];
    const int*   oov   = (const int*)d_in[27];

    float* out   = (float*)d_out;
    float* fd    = out;
    float* hnext = out + O_HN;
    float* wctx  = out + O_WCTX;
    float* wattn = out + O_WATTN;
    float* pgen  = out + O_PGEN;
    float* wcov  = out + O_WCOV;

    float* ws     = (float*)d_ws;
    float* yemb   = ws;
    float* gi     = yemb + B * EMB;
    float* gh     = gi + B * H3;
    float* dpw    = gh + B * H3;
    float* dps    = dpw + B * H;
    float* wscore = dps + B * H;
    float* sscore = wscore + B * L;
    float* sctx   = sscore + B * S;
    float* hid    = sctx + B * M;
    float* logits = hid + B * H;
    float* cat    = gi;      // gi consumed by k_gates before cat is written
    float* ctxp   = logits;  // ctxp consumed by k_ctxcat before logits written
    short* wb     = (short*)(logits + (size_t)B * V);
    short* wb_ih  = wb;
    short* wb_hh  = wb_ih + H3 * EMB;
    short* wb_dpw = wb_hh + H3 * H;
    short* wb_dps = wb_dpw + H * H;
    short* wb_mpw = wb_dps + H * H;
    short* wb_mps = wb_mpw + H * M;
    short* wb_v1  = wb_mps + H * M;
    float* pm     = (float*)(wb_v1 + H * H3);
    float* psum   = pm + B * 10;
    short* wmb_t  = (short*)(psum + B * 10);       // 400 tiles * 65536 shorts
    short* smb_t  = wmb_t + 400 * 65536;           // 30 tiles
    short* wmp_t  = smb_t + 30 * 65536;            // 2 * 131072
    short* smp_t  = wmp_t + 2 * 131072;
    size_t NEED = (size_t)((char*)(smp_t + 2 * 131072) - (char*)d_ws);
    bool big = ws_size >= NEED;

    k_setup<<<2583 + 1376, 256, 0, stream>>>(bih, bhh, bdpw, bdps, vd1b, emb, y,
                                             gi, gh, dpw, dps, hid, wscore, sscore, yemb,
                                             Wih, Whh, Wdpw, Wdps, Wmpw, Wmps, vd1w,
                                             wb_ih, wb_hh, wb_dpw, wb_dps, wb_mpw, wb_mps, wb_v1);
    // gi += yemb@Wih^T ; gh += h@Whh^T (+ fused wmb/smb tiled-bf16 conversion)
    int cvt1 = big ? 13760 : 0;  // (400+30) tiles * 8192 granules / 256
    k_mmsk<<<36 + cvt1, 256, 0, stream>>>(yemb, wb_ih, gi, 128, 12, 1,
                                          h, wb_hh, gh, 512, 12, 2,
                                          36, wmb, wmb_t, 400, smb, smb_t, 7);
    k_gates<<<256, 256, 0, stream>>>(gi, gh, h, hnext);
    // dpw, dps (+ fused wmp/smp tiled conversion)
    int cvt2 = big ? 256 : 0;    // 4 tiles(TR=256) * 16384 granules / 256
    k_mmsk<<<16 + cvt2, 256, 0, stream>>>(hnext, wb_dpw, dpw, 512, 4, 2,
                                          hnext, wb_dps, dps, 512, 4, 2,
                                          16, Wmpw, wmp_t, 2, Wmps, smp_t, 8);
    if (big)
        k_feat_g<<<dim3(2, 430), 256, 0, stream>>>(wmb_t, wmp_t, dpw, cov, covp, vw, wscore,
                                                   smb_t, smp_t, dps, vs, sscore);
    else
        k_feat2<<<dim3(2, 430), 256, 0, stream>>>(wmb, wb_mpw, dpw, cov, covp, vw, wscore,
                                                  smb, wb_mps, dps, vs, sscore);
    k_smax_sent<<<2 * B, 256, 0, stream>>>(wscore, wmask, cov, wattn, wcov,
                                           sscore, smask, smb, sctx);
    k_ctx_part<<<dim3(4, B), 256, 0, stream>>>(wattn, wmb, ctxp);
    k_ctxcat<<<768 + B, 256, 0, stream>>>(ctxp, sctx, hnext, yemb, pw, pb,
                                          wctx, cat, pgen);
    // hid += cat@vd1w^T
    k_mmsk<<<24, 256, 0, stream>>>(cat, wb_v1, hid, 1536, 4, 6,
                                   nullptr, nullptr, nullptr, 64, 1, 0,
                                   24, nullptr, nullptr, 0, nullptr, nullptr, 0);
    k_mm128<<<(V + 127) / 128, 256, 0, stream>>>(hid, vd2w, vd2b, logits, H, V, V);
    k_vpart<<<dim3(10, B), 256, 0, stream>>>(logits, pm, psum);
    k_vwrite<<<dim3(25, B), 256, 0, stream>>>(logits, pm, psum, pgen, fd);
    k_scatter<<<200, 256, 0, stream>>>(oov, wattn, pgen, fd);
}

// Round 8
// 218.066 us; speedup vs baseline: 1.2151x; 1.0678x over previous
//
#include <hip/hip_runtime.h>
#include <hip/hip_bf16.h>
#include <math.h>

#define B 128
#define L 400
#define S 30
#define V 50000
#define EMB 128
#define H 512
#define M 512
#define OOV 30
#define H3 1536
#define VO (V + OOV)
#define NTILE 391           // ceil(V/128)
#define NPART (2 * NTILE)   // per-row softmax partials
#define PSTRIDE 800

// ---- output layout (floats) ----
#define O_HN    (B * VO)
#define O_WCTX  (O_HN + B * H)
#define O_WATTN (O_WCTX + B * M)
#define O_PGEN  (O_WATTN + B * L)
#define O_WCOV  (O_PGEN + B)

typedef short bf16x8 __attribute__((ext_vector_type(8)));
typedef float f32x4 __attribute__((ext_vector_type(4)));

__device__ __forceinline__ unsigned pk2(float a, float b) {
    union { __hip_bfloat162 h; unsigned u; } cv;
    cv.h = __float22bfloat162_rn(make_float2(a, b));
    return cv.u;
}

__device__ __forceinline__ float fast_tanh(float x) {
    float e = __expf(2.f * x);
    return 1.f - 2.f * __builtin_amdgcn_rcpf(e + 1.f);
}

// ---- fused setup: bias-broadcast C buffers, zero scores, y-emb gather, weight cvt ----
__global__ void k_setup(const float* __restrict__ bih, const float* __restrict__ bhh,
                        const float* __restrict__ bdpw, const float* __restrict__ bdps,
                        const float* __restrict__ v1b, const float* __restrict__ emb,
                        const int* __restrict__ y,
                        float* gi, float* gh, float* dpw, float* dps, float* hid,
                        float* wscore, float* sscore, float* yemb,
                        const float* __restrict__ wih, const float* __restrict__ whh,
                        const float* __restrict__ wdpw, const float* __restrict__ wdps,
                        const float* __restrict__ wmpw, const float* __restrict__ wmps,
                        const float* __restrict__ v1,
                        short* o_ih, short* o_hh, short* o_dpw, short* o_dps,
                        short* o_mpw, short* o_mps, short* o_v1) {
    int bb = blockIdx.x;
    if (bb < 2583) {
        int i = bb * 256 + threadIdx.x;
        if (i < 196608) { gi[i] = bih[i % 1536]; return; }
        i -= 196608;
        if (i < 196608) { gh[i] = bhh[i % 1536]; return; }
        i -= 196608;
        if (i < 65536) { dpw[i] = bdpw[i & 511]; return; }
        i -= 65536;
        if (i < 65536) { dps[i] = bdps[i & 511]; return; }
        i -= 65536;
        if (i < 65536) { hid[i] = v1b[i & 511]; return; }
        i -= 65536;
        if (i < 51200) { wscore[i] = 0.f; return; }
        i -= 51200;
        if (i < 3840) { sscore[i] = 0.f; return; }
        i -= 3840;
        if (i < 16384) { int b = i >> 7, e = i & 127; yemb[i] = emb[(size_t)y[b] * EMB + e]; }
        return;
    }
    bb -= 2583;
    const float* src; short* dst;
    if      (bb < 96)  { src = wih;  dst = o_ih; }
    else if (bb < 480) { src = whh;  dst = o_hh;  bb -= 96; }
    else if (bb < 608) { src = wdpw; dst = o_dpw; bb -= 480; }
    else if (bb < 736) { src = wdps; dst = o_dps; bb -= 608; }
    else if (bb < 864) { src = wmpw; dst = o_mpw; bb -= 736; }
    else if (bb < 992) { src = wmps; dst = o_mps; bb -= 864; }
    else               { src = v1;   dst = o_v1;  bb -= 992; }
    size_t i = (size_t)bb * 2048 + threadIdx.x * 8;
    float4 a = *(const float4*)(src + i);
    float4 c = *(const float4*)(src + i + 4);
    uint4 w;
    w.x = pk2(a.x, a.y); w.y = pk2(a.z, a.w);
    w.z = pk2(c.x, c.y); w.w = pk2(c.z, c.w);
    *(uint4*)(dst + i) = w;
}

// stage 128 rows x 64 cols fp32 -> bf16 LDS [128][72]
__device__ __forceinline__ void stage_a(const float* __restrict__ src, int SK, int rmax,
                                        int t, short dst[128][72]) {
    int col = (t & 7) * 8;
    int r0 = t >> 3;
#pragma unroll
    for (int i = 0; i < 4; ++i) {
        int r = r0 + i * 32;
        int rr = r < rmax ? r : rmax;
        const float* p = src + (size_t)rr * SK + col;
        float4 a = *(const float4*)p;
        float4 c = *(const float4*)(p + 4);
        uint4 w;
        w.x = pk2(a.x, a.y); w.y = pk2(a.z, a.w);
        w.z = pk2(c.x, c.y); w.w = pk2(c.z, c.w);
        *(uint4*)&dst[r][col] = w;
    }
}

__device__ __forceinline__ void stage_b128bf(const short* __restrict__ src, int K,
                                             int t, short dst[128][72]) {
    int col = (t & 7) * 8;
    int r0 = t >> 3;
#pragma unroll
    for (int i = 0; i < 4; ++i) {
        int r = r0 + i * 32;
        *(bf16x8*)&dst[r][col] = *(const bf16x8*)(src + (size_t)r * K + col);
    }
}

// ---------- split-K skinny GEMM (M=128): C += A @ Bw^T, atomics, 2 fused jobs ----------
__global__ __launch_bounds__(256, 2) void k_mmsk(
        const float* __restrict__ A0, const short* __restrict__ B0, float* __restrict__ C0,
        int K0, int NT0, int KB0,
        const float* __restrict__ A1, const short* __restrict__ B1, float* __restrict__ C1,
        int K1, int NT1, int KB1) {
    __shared__ short As[128][72];
    __shared__ short Bs[128][72];
    int t = threadIdx.x, lane = t & 63, wv = t >> 6;
    int wr = wv >> 1, wc = wv & 1;
    int l15 = lane & 15, l4 = lane >> 4;

    int bb = blockIdx.x;
    const float* A; const short* Bb; float* C; int K, NT, KB;
    if (bb < NT0 * KB0) { A = A0; Bb = B0; C = C0; K = K0; NT = NT0; KB = KB0; }
    else { bb -= NT0 * KB0; A = A1; Bb = B1; C = C1; K = K1; NT = NT1; KB = KB1; }
    int nIdx = bb % NT, kIdx = bb / NT;
    int ldc = NT * 128;
    int nBase = nIdx * 128;
    int KC = K / KB;
    int kLo = kIdx * KC, kHi = kLo + KC;

    f32x4 acc[4][4] = {};
    for (int kc = kLo; kc < kHi; kc += 64) {
        stage_a(A + kc, K, 127, t, As);
        stage_b128bf(Bb + (size_t)nBase * K + kc, K, t, Bs);
        __syncthreads();
#pragma unroll
        for (int kk = 0; kk < 2; ++kk) {
            bf16x8 af[4], bq[4];
#pragma unroll
            for (int i = 0; i < 4; ++i)
                af[i] = *(const bf16x8*)&As[wr * 64 + i * 16 + l15][kk * 32 + l4 * 8];
#pragma unroll
            for (int j = 0; j < 4; ++j)
                bq[j] = *(const bf16x8*)&Bs[wc * 64 + j * 16 + l15][kk * 32 + l4 * 8];
#pragma unroll
            for (int i = 0; i < 4; ++i)
#pragma unroll
                for (int j = 0; j < 4; ++j)
                    acc[i][j] = __builtin_amdgcn_mfma_f32_16x16x32_bf16(
                        af[i], bq[j], acc[i][j], 0, 0, 0);
        }
        __syncthreads();
    }
#pragma unroll
    for (int i = 0; i < 4; ++i)
#pragma unroll
        for (int r = 0; r < 4; ++r) {
            int row = wr * 64 + i * 16 + l4 * 4 + r;
#pragma unroll
            for (int j = 0; j < 4; ++j) {
                int n = nBase + wc * 64 + j * 16 + l15;
                atomicAdd(&C[(size_t)row * ldc + n], acc[i][j][r]);
            }
        }
}

// ---------- vocab logits GEMM + fused per-tile softmax partials ----------
__global__ __launch_bounds__(256, 4) void k_mm128(
        const float* __restrict__ Ap, const float* __restrict__ Bf,
        const float* __restrict__ bias, float* __restrict__ C,
        float* __restrict__ pm, float* __restrict__ ps) {
    __shared__ short As[128][72];
    __shared__ short Bs[128][72];
    int t = threadIdx.x, lane = t & 63, wv = t >> 6;
    int wr = wv >> 1, wc = wv & 1;
    int l15 = lane & 15, l4 = lane >> 4;
    int nBase = blockIdx.x * 128;
    int brmax = V - 1 - nBase; if (brmax > 127) brmax = 127;

    f32x4 acc[4][4] = {};
    for (int kc = 0; kc < H; kc += 64) {
        stage_a(Ap + kc, H, 127, t, As);
        stage_a(Bf + (size_t)nBase * H + kc, H, brmax, t, Bs);
        __syncthreads();
#pragma unroll
        for (int kk = 0; kk < 2; ++kk) {
            bf16x8 af[4], bq[4];
#pragma unroll
            for (int i = 0; i < 4; ++i)
                af[i] = *(const bf16x8*)&As[wr * 64 + i * 16 + l15][kk * 32 + l4 * 8];
#pragma unroll
            for (int j = 0; j < 4; ++j)
                bq[j] = *(const bf16x8*)&Bs[wc * 64 + j * 16 + l15][kk * 32 + l4 * 8];
#pragma unroll
            for (int i = 0; i < 4; ++i)
#pragma unroll
                for (int j = 0; j < 4; ++j)
                    acc[i][j] = __builtin_amdgcn_mfma_f32_16x16x32_bf16(
                        af[i], bq[j], acc[i][j], 0, 0, 0);
        }
        __syncthreads();
    }
#pragma unroll
    for (int i = 0; i < 4; ++i)
#pragma unroll
        for (int r = 0; r < 4; ++r) {
            int row = wr * 64 + i * 16 + l4 * 4 + r;
            float val[4];
            float mrow = -3e38f;
#pragma unroll
            for (int j = 0; j < 4; ++j) {
                int n = nBase + wc * 64 + j * 16 + l15;
                val[j] = acc[i][j][r] + bias[n < V ? n : 0];
                if (n < V) {
                    C[(size_t)row * V + n] = val[j];
                    mrow = fmaxf(mrow, val[j]);
                }
            }
            float srow = 0.f;
#pragma unroll
            for (int j = 0; j < 4; ++j) {
                int n = nBase + wc * 64 + j * 16 + l15;
                if (n < V) srow += __expf(val[j] - mrow);
            }
#pragma unroll
            for (int off = 1; off < 16; off <<= 1) {
                float mo = __shfl_xor(mrow, off, 16), so = __shfl_xor(srow, off, 16);
                float mn = fmaxf(mrow, mo);
                srow = srow * __expf(mrow - mn) + so * __expf(mo - mn);
                mrow = mn;
            }
            if (l15 == 0) {
                int idx = blockIdx.x * 2 + wc;
                pm[row * PSTRIDE + idx] = mrow;
                ps[row * PSTRIDE + idx] = srow;
            }
        }
}

// ---------- fused word+sent attention feature GEMM + tanh + v-dot ----------
// 128 rows x 256 d-cols, K=512; T14 async-stage: next-chunk loads issued before MFMA.
__global__ __launch_bounds__(256, 2) void k_feat(
        const float* __restrict__ wmb, const short* __restrict__ wbmpw,
        const float* __restrict__ dpw, const float* __restrict__ cov,
        const float* __restrict__ covp, const float* __restrict__ vw,
        float* __restrict__ wscore,
        const float* __restrict__ smb, const short* __restrict__ wbmps,
        const float* __restrict__ dps, const float* __restrict__ vs,
        float* __restrict__ sscore) {
    __shared__ short As[128][72];
    __shared__ short Bs[256][72];
    int t = threadIdx.x, lane = t & 63, wv = t >> 6;
    int wr = wv >> 1, wc = wv & 1;
    int l15 = lane & 15, l4 = lane >> 4;

    bool word = blockIdx.y < 400;
    const float* Ap; const short* Bbf; const float* dproj; const float* vvec; float* outp;
    int rowBase;
    if (word) { Ap = wmb; Bbf = wbmpw; dproj = dpw; vvec = vw; outp = wscore; rowBase = blockIdx.y * 128; }
    else      { Ap = smb; Bbf = wbmps; dproj = dps; vvec = vs; outp = sscore; rowBase = (blockIdx.y - 400) * 128; }
    int nBase = blockIdx.x * 256;
    const float* Asrc = Ap + (size_t)rowBase * 512;
    const short* Bsrc = Bbf + (size_t)nBase * 512;

    int col = (t & 7) * 8;
    int r0 = t >> 3;

    float4 pa[4][2];
    bf16x8 pb[8];
    auto loadA = [&](int kc) {
#pragma unroll
        for (int i = 0; i < 4; ++i) {
            const float* p = Asrc + (size_t)(r0 + i * 32) * 512 + kc * 64 + col;
            pa[i][0] = *(const float4*)p;
            pa[i][1] = *(const float4*)(p + 4);
        }
    };
    auto loadB = [&](int kc) {
#pragma unroll
        for (int i = 0; i < 8; ++i)
            pb[i] = *(const bf16x8*)(Bsrc + (size_t)(r0 + i * 32) * 512 + kc * 64 + col);
    };
    auto writeLDS = [&]() {
#pragma unroll
        for (int i = 0; i < 4; ++i) {
            uint4 w;
            w.x = pk2(pa[i][0].x, pa[i][0].y); w.y = pk2(pa[i][0].z, pa[i][0].w);
            w.z = pk2(pa[i][1].x, pa[i][1].y); w.w = pk2(pa[i][1].z, pa[i][1].w);
            *(uint4*)&As[r0 + i * 32][col] = w;
        }
#pragma unroll
        for (int i = 0; i < 8; ++i)
            *(bf16x8*)&Bs[r0 + i * 32][col] = pb[i];
    };

    f32x4 acc[4][8] = {};
    loadA(0); loadB(0);
    for (int kc = 0; kc < 8; ++kc) {
        writeLDS();
        __syncthreads();
        if (kc < 7) { loadA(kc + 1); loadB(kc + 1); }  // async: hides under MFMA
#pragma unroll
        for (int kk = 0; kk < 2; ++kk) {
            bf16x8 af[4], bq[8];
#pragma unroll
            for (int i = 0; i < 4; ++i)
                af[i] = *(const bf16x8*)&As[wr * 64 + i * 16 + l15][kk * 32 + l4 * 8];
#pragma unroll
            for (int j = 0; j < 8; ++j)
                bq[j] = *(const bf16x8*)&Bs[wc * 128 + j * 16 + l15][kk * 32 + l4 * 8];
#pragma unroll
            for (int i = 0; i < 4; ++i)
#pragma unroll
                for (int j = 0; j < 8; ++j)
                    acc[i][j] = __builtin_amdgcn_mfma_f32_16x16x32_bf16(
                        af[i], bq[j], acc[i][j], 0, 0, 0);
        }
        __syncthreads();
    }
    int dB = nBase + wc * 128;
    float vv[8], cp[8], dp0[8], dp1[8];
    int b0 = word ? rowBase / 400 : 0;
    int b1 = word ? (rowBase + 127) / 400 : 0;
#pragma unroll
    for (int j = 0; j < 8; ++j) {
        int d = dB + j * 16 + l15;
        vv[j] = vvec[d];
        cp[j] = word ? covp[d] : 0.f;
        if (word) { dp0[j] = dproj[b0 * H + d]; dp1[j] = dproj[b1 * H + d]; }
    }
#pragma unroll
    for (int i = 0; i < 4; ++i) {
#pragma unroll
        for (int r = 0; r < 4; ++r) {
            int row = rowBase + wr * 64 + i * 16 + l4 * 4 + r;
            int b = word ? (row / 400) : (row / 30);
            float cv = word ? cov[row] : 0.f;
            bool use0 = (b == b0);
            float s = 0.f;
#pragma unroll
            for (int j = 0; j < 8; ++j) {
                float dpv = word ? (use0 ? dp0[j] : dp1[j])
                                 : dproj[b * H + dB + j * 16 + l15];
                float f = acc[i][j][r] + dpv + cv * cp[j];
                s += vv[j] * fast_tanh(f);
            }
            s += __shfl_xor(s, 8, 16);
            s += __shfl_xor(s, 4, 16);
            s += __shfl_xor(s, 2, 16);
            s += __shfl_xor(s, 1, 16);
            if (l15 == 0) atomicAdd(&outp[row], s);
        }
    }
}

__global__ void k_gates(const float* __restrict__ gi, const float* __restrict__ gh,
                        const float* __restrict__ h, float* __restrict__ hnext) {
    int i = blockIdx.x * 256 + threadIdx.x;
    int b = i >> 9, k = i & 511;
    float ir = gi[b * H3 + k], iz = gi[b * H3 + H + k], inn = gi[b * H3 + 2 * H + k];
    float hr = gh[b * H3 + k], hz = gh[b * H3 + H + k], hn = gh[b * H3 + 2 * H + k];
    float r = 1.f / (1.f + __expf(-(ir + hr)));
    float z = 1.f / (1.f + __expf(-(iz + hz)));
    float n = fast_tanh(inn + r * hn);
    hnext[i] = (1.f - z) * n + z * h[i];
}

// fused: blocks [0,B) word masked-softmax+coverage; [B,2B) sent softmax+ctx
__global__ __launch_bounds__(256) void k_smax_sent(
        const float* __restrict__ wscore, const float* __restrict__ wmask,
        const float* __restrict__ cov, float* __restrict__ wattn, float* __restrict__ wcov,
        const float* __restrict__ sscore, const float* __restrict__ smask,
        const float* __restrict__ smb, float* __restrict__ sctx) {
    __shared__ float sc[L];
    __shared__ float red[4];
    int t = threadIdx.x;
    if (blockIdx.x < B) {
        int b = blockIdx.x;
        float mx = -1e30f;
        for (int l = t; l < L; l += 256) { float s = wscore[b * L + l]; sc[l] = s; mx = fmaxf(mx, s); }
        for (int off = 32; off; off >>= 1) mx = fmaxf(mx, __shfl_xor(mx, off));
        if ((t & 63) == 0) red[t >> 6] = mx;
        __syncthreads();
        mx = fmaxf(fmaxf(red[0], red[1]), fmaxf(red[2], red[3]));
        __syncthreads();
        float sm = 0.f;
        for (int l = t; l < L; l += 256) { float e = __expf(sc[l] - mx); sc[l] = e; sm += e; }
        for (int off = 32; off; off >>= 1) sm += __shfl_xor(sm, off);
        if ((t & 63) == 0) red[t >> 6] = sm;
        __syncthreads();
        float Z = red[0] + red[1] + red[2] + red[3];
        __syncthreads();
        float sm2 = 0.f;
        for (int l = t; l < L; l += 256) {
            float a = (sc[l] / Z) * wmask[b * L + l];
            sc[l] = a; sm2 += a;
        }
        for (int off = 32; off; off >>= 1) sm2 += __shfl_xor(sm2, off);
        if ((t & 63) == 0) red[t >> 6] = sm2;
        __syncthreads();
        float Zm = red[0] + red[1] + red[2] + red[3] + 1e-10f;
        for (int l = t; l < L; l += 256) {
            float a = sc[l] / Zm;
            wattn[b * L + l] = a;
            wcov[b * L + l] = cov[b * L + l] + a;
        }
    } else {
        int b = blockIdx.x - B;
        float* sa = sc; float* sa2 = sc + 32; float* smk = sc + 64;
        if (t < S) { sa[t] = sscore[b * S + t]; smk[t] = smask[b * S + t]; }
        __syncthreads();
        if (t < S) {
            float mx = -1e30f;
            for (int l = 0; l < S; ++l) mx = fmaxf(mx, sa[l]);
            float Z = 0.f, Zm = 0.f;
            for (int l = 0; l < S; ++l) { float e = __expf(sa[l] - mx); Z += e; Zm += e * smk[l]; }
            float e = __expf(sa[t] - mx);
            float a = (e / Z) * smk[t];
            sa2[t] = a / (Zm / Z + 1e-10f);
        }
        __syncthreads();
        float a0 = 0.f, a1 = 0.f;
        for (int l = 0; l < S; ++l) {
            const float* r = smb + ((size_t)b * S + l) * M;
            float a = sa2[l];
            a0 += a * r[t]; a1 += a * r[t + 256];
        }
        sctx[b * M + t] = a0; sctx[b * M + t + 256] = a1;
    }
}

// ctx partials: grid (4, B)
__global__ __launch_bounds__(256) void k_ctx_part(
        const float* __restrict__ attn, const float* __restrict__ memb,
        float* __restrict__ ctxp) {
    __shared__ float sa[100];
    int b = blockIdx.y, ch = blockIdx.x, t = threadIdx.x;
    int l0 = ch * 100;
    if (t < 100) sa[t] = attn[b * L + l0 + t];
    __syncthreads();
    float ax = 0.f, ay = 0.f;
    const float* base = memb + ((size_t)b * L + l0) * M + t * 2;
#pragma unroll 4
    for (int l = 0; l < 100; ++l) {
        float2 m2 = *(const float2*)(base + (size_t)l * M);
        float a = sa[l];
        ax += a * m2.x; ay += a * m2.y;
    }
    float* o = ctxp + ((size_t)(ch * B + b)) * M + t * 2;
    o[0] = ax; o[1] = ay;
}

// fused: [0,256) ctx reduce -> wctx + cat[:,0:512]; [256,768) cat[:,512:1536]; [768,768+B) p_gen
__global__ void k_ctxcat(const float* __restrict__ ctxp, const float* __restrict__ sctx,
                         const float* __restrict__ hnext, const float* __restrict__ yemb,
                         const float* __restrict__ pw, const float* __restrict__ pb,
                         float* __restrict__ wctx, float* __restrict__ cat,
                         float* __restrict__ pg) {
    int bb = blockIdx.x, t = threadIdx.x;
    if (bb < 256) {
        int j = bb * 256 + t;  // B*M
        float v = ctxp[j] + ctxp[B * M + j] + ctxp[2 * B * M + j] + ctxp[3 * B * M + j];
        wctx[j] = v;
        int b = j >> 9, c = j & 511;
        cat[b * H3 + c] = v;
    } else if (bb < 768) {
        int i = (bb - 256) * 256 + t;  // B*1024
        int b = i >> 10, c = i & 1023;
        cat[b * H3 + 512 + c] = (c < 512) ? sctx[b * 512 + c] : hnext[b * 512 + c - 512];
    } else {
        int b = bb - 768;
        if (t < 64) {
            float s = 0.f;
            for (int i = t; i < EMB + H + 2 * M; i += 64) {
                float x;
                if (i < 512) {
                    int j = b * 512 + i;
                    x = ctxp[j] + ctxp[B * M + j] + ctxp[2 * B * M + j] + ctxp[3 * B * M + j];
                } else if (i < 1024) x = sctx[b * 512 + i - 512];
                else if (i < 1536)   x = hnext[b * 512 + i - 1024];
                else                 x = yemb[b * EMB + i - 1536];
                s += x * pw[i];
            }
            for (int off = 32; off; off >>= 1) s += __shfl_xor(s, off);
            if (t == 0) pg[b] = 1.f / (1.f + __expf(-(s + pb[0])));
        }
    }
}

// final dist write: grid (25, B); reduces 782 partials then one logits pass
__global__ __launch_bounds__(256) void k_vwrite(
        const float* __restrict__ logits, const float* __restrict__ pm,
        const float* __restrict__ ps, const float* __restrict__ pgen,
        float* __restrict__ fd) {
    __shared__ float wm[4], wsv[4];
    int b = blockIdx.y, t = threadIdx.x;
    float m = -3e38f, s = 0.f;
    for (int i = t; i < NPART; i += 256) {
        float mo = pm[b * PSTRIDE + i], so = ps[b * PSTRIDE + i];
        float mn = fmaxf(m, mo);
        s = s * __expf(m - mn) + so * __expf(mo - mn);
        m = mn;
    }
    for (int off = 32; off; off >>= 1) {
        float mo = __shfl_xor(m, off), so = __shfl_xor(s, off);
        float mn = fmaxf(m, mo);
        s = s * __expf(m - mn) + so * __expf(mo - mn);
        m = mn;
    }
    if ((t & 63) == 0) { wm[t >> 6] = m; wsv[t >> 6] = s; }
    __syncthreads();
    float M2 = fmaxf(fmaxf(wm[0], wm[1]), fmaxf(wm[2], wm[3]));
    float S2 = wsv[0] * __expf(wm[0] - M2) + wsv[1] * __expf(wm[1] - M2) +
               wsv[2] * __expf(wm[2] - M2) + wsv[3] * __expf(wm[3] - M2);
    float inv = pgen[b] / S2;
    int col0 = blockIdx.x * 2048 + t * 8;
    float* outb = fd + (size_t)b * VO;
    if (col0 + 8 <= V) {
        const float4* lp = (const float4*)(logits + (size_t)b * V + col0);
        float4 x = lp[0], z = lp[1];
        *(float2*)(outb + col0)     = make_float2(inv * __expf(x.x - M2), inv * __expf(x.y - M2));
        *(float2*)(outb + col0 + 2) = make_float2(inv * __expf(x.z - M2), inv * __expf(x.w - M2));
        *(float2*)(outb + col0 + 4) = make_float2(inv * __expf(z.x - M2), inv * __expf(z.y - M2));
        *(float2*)(outb + col0 + 6) = make_float2(inv * __expf(z.z - M2), inv * __expf(z.w - M2));
    } else {
#pragma unroll
        for (int k = 0; k < 8; k += 2) {
            int c = col0 + k;
            if (c + 2 <= VO) {
                float2 o;
                o.x = (c < V)     ? inv * __expf(logits[(size_t)b * V + c] - M2) : 0.f;
                o.y = (c + 1 < V) ? inv * __expf(logits[(size_t)b * V + c + 1] - M2) : 0.f;
                *(float2*)(outb + c) = o;
            }
        }
    }
}

__global__ void k_scatter(const int* __restrict__ oov, const float* __restrict__ wattn,
                          const float* __restrict__ pgen, float* __restrict__ fd) {
    int i = blockIdx.x * 256 + threadIdx.x;
    int b = i / L;
    float w = (1.f - pgen[b]) * wattn[i];
    atomicAdd(&fd[(size_t)b * VO + oov[i]], w);
}

extern "C" void kernel_launch(void* const* d_in, const int* in_sizes, int n_in,
                              void* d_out, int out_size, void* d_ws, size_t ws_size,
                              hipStream_t stream) {
    const float* h     = (const float*)d_in[0];
    const float* wmb   = (const float*)d_in[1];
    const float* smb   = (const float*)d_in[2];
    const float* wmask = (const float*)d_in[3];
    const float* smask = (const float*)d_in[4];
    const float* cov   = (const float*)d_in[5];
    const float* emb   = (const float*)d_in[6];
    const float* Wih   = (const float*)d_in[7];
    const float* Whh   = (const float*)d_in[8];
    const float* bih   = (const float*)d_in[9];
    const float* bhh   = (const float*)d_in[10];
    const float* Wmpw  = (const float*)d_in[11];
    const float* Wdpw  = (const float*)d_in[12];
    const float* bdpw  = (const float*)d_in[13];
    const float* vw    = (const float*)d_in[14];
    const float* covp  = (const float*)d_in[15];
    const float* Wmps  = (const float*)d_in[16];
    const float* Wdps  = (const float*)d_in[17];
    const float* bdps  = (const float*)d_in[18];
    const float* vs    = (const float*)d_in[19];
    const float* pw    = (const float*)d_in[20];
    const float* pb    = (const float*)d_in[21];
    const float* vd1w  = (const float*)d_in[22];
    const float* vd1b  = (const float*)d_in[23];
    const float* vd2w  = (const float*)d_in[24];
    const float* vd2b  = (const float*)d_in[25];
    const int*   y     = (const int*)d_in[26];
    const int*   oov   = (const int*)d_in[27];

    float* out   = (float*)d_out;
    float* fd    = out;
    float* hnext = out + O_HN;
    float* wctx  = out + O_WCTX;
    float* wattn = out + O_WATTN;
    float* pgen  = out + O_PGEN;
    float* wcov  = out + O_WCOV;

    float* ws     = (float*)d_ws;
    float* yemb   = ws;
    float* gi     = yemb + B * EMB;
    float* gh     = gi + B * H3;
    float* dpw    = gh + B * H3;
    float* dps    = dpw + B * H;
    float* wscore = dps + B * H;
    float* sscore = wscore + B * L;
    float* sctx   = sscore + B * S;
    float* hid    = sctx + B * M;
    float* logits = hid + B * H;
    float* cat    = gi;      // gi consumed by k_gates before cat is written
    float* ctxp   = logits;  // ctxp consumed by k_ctxcat before logits written
    short* wb     = (short*)(logits + (size_t)B * V);
    short* wb_ih  = wb;
    short* wb_hh  = wb_ih + H3 * EMB;
    short* wb_dpw = wb_hh + H3 * H;
    short* wb_dps = wb_dpw + H * H;
    short* wb_mpw = wb_dps + H * H;
    short* wb_mps = wb_mpw + H * M;
    short* wb_v1  = wb_mps + H * M;
    float* pm     = (float*)(wb_v1 + H * H3);   // B * PSTRIDE
    float* psum   = pm + B * PSTRIDE;

    k_setup<<<2583 + 1376, 256, 0, stream>>>(bih, bhh, bdpw, bdps, vd1b, emb, y,
                                             gi, gh, dpw, dps, hid, wscore, sscore, yemb,
                                             Wih, Whh, Wdpw, Wdps, Wmpw, Wmps, vd1w,
                                             wb_ih, wb_hh, wb_dpw, wb_dps, wb_mpw, wb_mps, wb_v1);
    // gi += yemb@Wih^T (12 tiles, K=128) ; gh += h@Whh^T (12 tiles, K=512, ksplit 2)
    k_mmsk<<<36, 256, 0, stream>>>(yemb, wb_ih, gi, 128, 12, 1,
                                   h, wb_hh, gh, 512, 12, 2);
    k_gates<<<256, 256, 0, stream>>>(gi, gh, h, hnext);
    // dpw, dps: each 4 tiles, K=512, ksplit 2
    k_mmsk<<<16, 256, 0, stream>>>(hnext, wb_dpw, dpw, 512, 4, 2,
                                   hnext, wb_dps, dps, 512, 4, 2);
    k_feat<<<dim3(2, 430), 256, 0, stream>>>(wmb, wb_mpw, dpw, cov, covp, vw, wscore,
                                             smb, wb_mps, dps, vs, sscore);
    k_smax_sent<<<2 * B, 256, 0, stream>>>(wscore, wmask, cov, wattn, wcov,
                                           sscore, smask, smb, sctx);
    k_ctx_part<<<dim3(4, B), 256, 0, stream>>>(wattn, wmb, ctxp);
    k_ctxcat<<<768 + B, 256, 0, stream>>>(ctxp, sctx, hnext, yemb, pw, pb,
                                          wctx, cat, pgen);
    // hid += cat@vd1w^T (4 tiles, K=1536, ksplit 6)
    k_mmsk<<<24, 256, 0, stream>>>(cat, wb_v1, hid, 1536, 4, 6,
                                   nullptr, nullptr, nullptr, 64, 1, 0);
    k_mm128<<<NTILE, 256, 0, stream>>>(hid, vd2w, vd2b, logits, pm, psum);
    k_vwrite<<<dim3(25, B), 256, 0, stream>>>(logits, pm, psum, pgen, fd);
    k_scatter<<<200, 256, 0, stream>>>(oov, wattn, pgen, fd);
}